// Round 13
// baseline (970.376 us; speedup 1.0000x reference)
//
#include <hip/hip_runtime.h>

// VectorQuantizer on MI355X (gfx950)
// z:   [B=128, C=128, H=32, W=32] f32 -> pixel n = b*1024 + hw, channel stride 1024
// emb: [K=256, C=128] f32
// out: [quantized_st 16777216][indices 131072][commit 1][codebook 1] (f32)
//
// Exactness contract (verified absmax=0 rounds 2-12 -- DO NOT CHANGE):
//   d_k = fl( fl(zz - 2*s_k) + ee_k )
//   s_k = sequential fmaf over c ascending; zz = sequential fl(z*z) sum
//   first-occurrence argmin == min over u64 keys (d_bits<<32 | k), d > 0
//
// Round-13 = r11 GEMM tile with OCCUPANCY doubled: CCH=16 -> LDS 21KB ->
// 5 blocks/CU (was 42KB -> 3). es rows = 8 B64 slots, swizzle key
// ((code>>3)^code)&7: staging writes <=2-way (free), reads clean per-8-lane.
// e-gather sequential/coalesced (r12's rotation reverted: it cost +48MB FETCH).

typedef float f32x4 __attribute__((ext_vector_type(4)));
typedef float f32x2 __attribute__((ext_vector_type(2)));
typedef unsigned long long u64;

#define VQ_C      128
#define VQ_K      256
#define VQ_HW     1024
#define VQ_CHW    (VQ_C * VQ_HW)
#define VQ_NPIX   131072
#define VQ_QELEMS 16777216
#define PXB       64
#define NBLK      (VQ_NPIX / PXB)     // 2048
#define CCH       16                  // channels per chunk
#define NCH       8

// ws layout (floats): [0..255] ee[k]; [256..256+NBLK) per-block loss partials
__global__ void vq_prep(const float* __restrict__ emb, float* __restrict__ ws) {
    int k = threadIdx.x;               // 256 threads = 256 codes
    float s = 0.0f;
#pragma unroll
    for (int c = 0; c < VQ_C; ++c) {
        float e = emb[k * VQ_C + c];
        s = __fadd_rn(s, __fmul_rn(e, e));
    }
    ws[k] = s;
}

__global__ __launch_bounds__(256, 5) void vq_main(const float* __restrict__ z,
                                                  const float* __restrict__ emb,
                                                  const float* __restrict__ ee,
                                                  float* __restrict__ partials,
                                                  float* __restrict__ out) {
    __shared__ float zs[CCH * PXB];        // [c][px], 4 KB
    __shared__ char  es[VQ_K * CCH * 4];   // b64-slot swizzled e tile, 16 KB
    __shared__ float zzs[PXB];
    __shared__ int   iminS[PXB];
    __shared__ float red[4];

    const int tx = threadIdx.x;
    const int cg = tx & 31;                // code group: codes cg*8 .. +8
    const int pg = tx >> 5;                // px group:  px  pg*8 .. +8
    const int n0 = blockIdx.x * PXB;
    const int b  = n0 >> 10;
    const int hw0 = n0 & 1023;             // 64 | 1024 -> no b straddle
    const float* __restrict__ zb = z + (size_t)b * VQ_CHW + hw0;

    // ---- phase A: zz per pixel, exact sequential chain (wave 0; first
    //      in-loop barrier orders it before any consumer)
    if (tx < PXB) {
        float zz = 0.0f;
#pragma unroll
        for (int c = 0; c < VQ_C; ++c) {
            float v = zb[c * VQ_HW + tx];  // 64-lane coalesced per c
            zz = __fadd_rn(zz, __fmul_rn(v, v));
        }
        zzs[tx] = zz;
    }

    float acc[8][8];
#pragma unroll
    for (int p = 0; p < 8; ++p)
#pragma unroll
        for (int o = 0; o < 8; ++o) acc[p][o] = 0.0f;

    const int ci   = tx >> 6;              // z-staging c-lane (wave id)
    const int px   = tx & 63;
    const int wkey = ((tx >> 3) ^ tx) & 7; // es write swizzle key (this code)

#pragma unroll 1
    for (int ch = 0; ch < NCH; ++ch) {
        const int c0 = ch * CCH;
        if (ch) __syncthreads();           // protect tiles from overwrite

        // ---- stage z tile [c][px]: coalesced global reads, 2-way LDS writes
#pragma unroll
        for (int i = 0; i < 4; ++i) {
            int c = i * 4 + ci;
            zs[c * PXB + px] = zb[(c0 + c) * VQ_HW + px];
        }
        // ---- stage e tile: thread tx = code; SEQUENTIAL loads (coalesced),
        //      b64 slot writes at (m ^ wkey): <=2-way per 32 lanes (free)
        {
            const float* __restrict__ eg = emb + tx * VQ_C + c0;
            f32x4 v0 = *(const f32x4*)(eg + 0);
            f32x4 v1 = *(const f32x4*)(eg + 4);
            f32x4 v2 = *(const f32x4*)(eg + 8);
            f32x4 v3 = *(const f32x4*)(eg + 12);
            char* erow = es + tx * 64;
            f32x2 w0 = {v0[0], v0[1]}, w1 = {v0[2], v0[3]};
            f32x2 w2 = {v1[0], v1[1]}, w3 = {v1[2], v1[3]};
            f32x2 w4 = {v2[0], v2[1]}, w5 = {v2[2], v2[3]};
            f32x2 w6 = {v3[0], v3[1]}, w7 = {v3[2], v3[3]};
            *(f32x2*)(erow + (((0 ^ wkey)) << 3)) = w0;
            *(f32x2*)(erow + (((1 ^ wkey)) << 3)) = w1;
            *(f32x2*)(erow + (((2 ^ wkey)) << 3)) = w2;
            *(f32x2*)(erow + (((3 ^ wkey)) << 3)) = w3;
            *(f32x2*)(erow + (((4 ^ wkey)) << 3)) = w4;
            *(f32x2*)(erow + (((5 ^ wkey)) << 3)) = w5;
            *(f32x2*)(erow + (((6 ^ wkey)) << 3)) = w6;
            *(f32x2*)(erow + (((7 ^ wkey)) << 3)) = w7;
        }
        __syncthreads();

        // ---- compute: 4 windows of 4 channels
#pragma unroll 1
        for (int c4 = 0; c4 < 4; ++c4) {
            f32x4 zf[4][2];                // [j][half]: 8 px of channel c4*4+j
#pragma unroll
            for (int j = 0; j < 4; ++j) {
                int c = c4 * 4 + j;
                zf[j][0] = *(const f32x4*)(zs + c * PXB + pg * 8);
                zf[j][1] = *(const f32x4*)(zs + c * PXB + pg * 8 + 4);
            }
            f32x2 ef[8][2];                // [o][half]: e[code][c4*4 + 0..3]
#pragma unroll
            for (int o = 0; o < 8; ++o) {
                int code = cg * 8 + o;
                int key  = (cg & 7) ^ o;   // == ((code>>3)^code)&7
                const char* erow = es + code * 64;
                ef[o][0] = *(const f32x2*)(erow + (((c4 * 2)     ^ key) << 3));
                ef[o][1] = *(const f32x2*)(erow + (((c4 * 2 + 1) ^ key) << 3));
            }
            // c ascending (j outer) => exact per-(px,code) fmaf chain
#pragma unroll
            for (int j = 0; j < 4; ++j)
#pragma unroll
                for (int o = 0; o < 8; ++o) {
                    float ev = ef[o][j >> 1][j & 1];
#pragma unroll
                    for (int h = 0; h < 2; ++h)
#pragma unroll
                        for (int i = 0; i < 4; ++i)
                            acc[h * 4 + i][o] =
                                fmaf(zf[j][h][i], ev, acc[h * 4 + i][o]);
                }
        }
    }

    // ---- d + first-occurrence argmin (u64 keys; d > 0 so bit order = value order)
    float eev[8];
#pragma unroll
    for (int o = 0; o < 8; ++o) eev[o] = ee[cg * 8 + o];

#pragma unroll
    for (int p = 0; p < 8; ++p) {
        float zz = zzs[pg * 8 + p];
        u64 key = ~0ull;
#pragma unroll
        for (int o = 0; o < 8; ++o) {
            float a = acc[p][o];
            float d = __fadd_rn(__fsub_rn(zz, __fadd_rn(a, a)), eev[o]);
            union { float f; unsigned u; } du; du.f = d;
            u64 k2 = ((u64)du.u << 32) | (unsigned)(cg * 8 + o);
            if (k2 < key) key = k2;
        }
        // reduce across the 32 code-group threads (one half-wave)
#pragma unroll
        for (int st = 1; st < 32; st <<= 1) {
            u64 o2 = __shfl_xor(key, st, 32);
            if (o2 < key) key = o2;
        }
        if (cg == 0) iminS[pg * 8 + p] = (int)(key & 0xffffffffu);
    }
    __syncthreads();

    // ---- epilogue: thread -> pixel tx&63, channel-block tx>>6 (32 channels)
    const int cb = tx >> 6;
    const int im = iminS[px];
    const float* __restrict__ eq = emb + (size_t)im * VQ_C + cb * 32;
    const float* __restrict__ zp = zb + px;
    float* __restrict__ op = out + (size_t)b * VQ_CHW + hw0 + px;
    float lsum = 0.0f;
#pragma unroll
    for (int i = 0; i < 8; ++i) {
        f32x4 e4 = *(const f32x4*)(eq + i * 4);        // divergent L2 gather
#pragma unroll
        for (int j = 0; j < 4; ++j) {
            int c = cb * 32 + i * 4 + j;
            float zv   = zp[c * VQ_HW];                // L2-hot, exact bits
            float diff = __fsub_rn(e4[j], zv);
            op[c * VQ_HW] = __fadd_rn(zv, diff);       // coalesced per c
            lsum = fmaf(diff, diff, lsum);
        }
    }
    if (tx < PXB) out[VQ_QELEMS + n0 + tx] = (float)iminS[tx];

    // ---- loss partial
#pragma unroll
    for (int off = 32; off > 0; off >>= 1) lsum += __shfl_down(lsum, off, 64);
    if ((tx & 63) == 0) red[tx >> 6] = lsum;
    __syncthreads();
    if (tx == 0)
        partials[blockIdx.x] = (red[0] + red[1]) + (red[2] + red[3]);
}

__global__ void vq_fin(const float* __restrict__ partials, float* __restrict__ out) {
    double acc = 0.0;
    for (int i = 0; i < NBLK; ++i) acc += (double)partials[i];
    float m = (float)(acc * (1.0 / (double)VQ_QELEMS));
    out[VQ_QELEMS + VQ_NPIX + 0] = 0.25f * m;  // commitment
    out[VQ_QELEMS + VQ_NPIX + 1] = m;          // codebook
}

extern "C" void kernel_launch(void* const* d_in, const int* in_sizes, int n_in,
                              void* d_out, int out_size, void* d_ws, size_t ws_size,
                              hipStream_t stream) {
    const float* z   = (const float*)d_in[0];
    const float* emb = (const float*)d_in[1];
    float* out = (float*)d_out;
    float* ws  = (float*)d_ws;            // [0..255]=ee, [256..)=partials

    vq_prep<<<1, 256, 0, stream>>>(emb, ws);
    vq_main<<<NBLK, 256, 0, stream>>>(z, emb, ws, ws + 256, out);
    vq_fin<<<1, 1, 0, stream>>>(ws + 256, out);
}

// Round 14
// 182.240 us; speedup vs baseline: 5.3247x; 5.3247x over previous
//
#include <hip/hip_runtime.h>

// VectorQuantizer on MI355X (gfx950)
// z:   [B=128, C=128, H=32, W=32] f32 -> pixel n = b*1024 + hw, channel stride 1024
// emb: [K=256, C=128] f32
// out: [quantized_st 16777216][indices 131072][commit 1][codebook 1] (f32)
//
// Exactness contract (verified absmax=0 rounds 2-13 -- DO NOT CHANGE):
//   d_k = fl( fl(zz - 2*s_k) + ee_k )
//   s_k = sequential fmaf over c ascending; zz = sequential fl(z*z) sum
//   first-occurrence argmin == min over u64 keys (d_bits<<32 | k), d > 0
//
// Round-14 = round-11 EXACTLY (174us, proven) + es row stride 128B -> 144B
// (8 slots + 16B pad). In 16B units addr/16 = 9*code + slot; 9 == 1 (mod 8)
// so the row index feeds the bank-group: writes (slot=c4^swx, sequential
// loads) hit (tx+c4)%8 per 8 lanes = distinct -> conflict-free; reads hit
// (o + c4^(cg&7))%8 = distinct -> conflict-free. Kills r11's 23.1M conflict
// cycles with ZERO change to load order / gather locality (r12's mistake).

typedef float f32x4 __attribute__((ext_vector_type(4)));
typedef unsigned long long u64;

#define VQ_C      128
#define VQ_K      256
#define VQ_HW     1024
#define VQ_CHW    (VQ_C * VQ_HW)
#define VQ_NPIX   131072
#define VQ_QELEMS 16777216
#define PXB       64
#define NBLK      (VQ_NPIX / PXB)     // 2048
#define CCH       32                  // channels per chunk
#define NCH       4
#define EROW      144                 // es row stride bytes (8x16B + 16B pad)

// ws layout (floats): [0..255] ee[k]; [256..256+NBLK) per-block loss partials
__global__ void vq_prep(const float* __restrict__ emb, float* __restrict__ ws) {
    int k = threadIdx.x;               // 256 threads = 256 codes
    float s = 0.0f;
#pragma unroll
    for (int c = 0; c < VQ_C; ++c) {
        float e = emb[k * VQ_C + c];
        s = __fadd_rn(s, __fmul_rn(e, e));
    }
    ws[k] = s;
}

__global__ __launch_bounds__(256, 3) void vq_main(const float* __restrict__ z,
                                                  const float* __restrict__ emb,
                                                  const float* __restrict__ ee,
                                                  float* __restrict__ partials,
                                                  float* __restrict__ out) {
    __shared__ float zs[CCH * PXB];        // [c][px], 8 KB
    __shared__ char  es[VQ_K * EROW];      // padded swizzled e tile, 36 KB
    __shared__ float zzs[PXB];
    __shared__ int   iminS[PXB];
    __shared__ float red[4];

    const int tx = threadIdx.x;
    const int cg = tx & 31;                // code group: codes cg*8 .. +8
    const int pg = tx >> 5;                // px group:  px  pg*8 .. +8
    const int n0 = blockIdx.x * PXB;
    const int b  = n0 >> 10;
    const int hw0 = n0 & 1023;             // 64 | 1024 -> no b straddle
    const float* __restrict__ zb = z + (size_t)b * VQ_CHW + hw0;

    // ---- phase A: zz per pixel, exact sequential chain (wave 0; ordered
    //      before consumers by the first in-loop barrier)
    if (tx < PXB) {
        float zz = 0.0f;
#pragma unroll
        for (int c = 0; c < VQ_C; ++c) {
            float v = zb[c * VQ_HW + tx];  // 64-lane coalesced per c
            zz = __fadd_rn(zz, __fmul_rn(v, v));
        }
        zzs[tx] = zz;
    }

    float acc[8][8];
#pragma unroll
    for (int p = 0; p < 8; ++p)
#pragma unroll
        for (int o = 0; o < 8; ++o) acc[p][o] = 0.0f;

    const int ci  = tx >> 6;               // z-staging c-lane (wave id)
    const int px  = tx & 63;
    const int swx = (tx >> 3) & 7;         // row's swizzle key

#pragma unroll 1
    for (int ch = 0; ch < NCH; ++ch) {
        const int c0 = ch * CCH;
        if (ch) __syncthreads();           // protect tiles from overwrite

        // ---- stage z tile [c][px]: coalesced global reads, free LDS writes
#pragma unroll
        for (int i = 0; i < 8; ++i) {
            int c = i * 4 + ci;
            zs[c * PXB + px] = zb[(c0 + c) * VQ_HW + px];
        }
        // ---- stage e tile: thread tx = code; SEQUENTIAL coalesced loads,
        //      swizzled slot + 144B row stride -> conflict-free writes
        {
            const float* __restrict__ eg = emb + tx * VQ_C + c0;
            char* erow = es + tx * EROW;
#pragma unroll
            for (int c4 = 0; c4 < 8; ++c4) {
                f32x4 v = *(const f32x4*)(eg + c4 * 4);
                int sw = ((c4 ^ swx) << 4);
                *(f32x4*)(erow + sw) = v;
            }
        }
        __syncthreads();

        // ---- compute: 8 windows of 4 channels
#pragma unroll 1
        for (int c4 = 0; c4 < 8; ++c4) {
            f32x4 zf[4][2];                // [j][half]: 8 px of channel c4*4+j
#pragma unroll
            for (int j = 0; j < 4; ++j) {
                int c = c4 * 4 + j;
                zf[j][0] = *(const f32x4*)(zs + c * PXB + pg * 8);
                zf[j][1] = *(const f32x4*)(zs + c * PXB + pg * 8 + 4);
            }
            f32x4 ef[8];                   // 8 codes x 4 channels
#pragma unroll
            for (int o = 0; o < 8; ++o) {
                int code = cg * 8 + o;
                int sw = ((c4 ^ ((code >> 3) & 7)) << 4);
                ef[o] = *(const f32x4*)(es + code * EROW + sw);
            }
            // c ascending (j outer) => exact per-(px,code) fmaf chain
#pragma unroll
            for (int j = 0; j < 4; ++j)
#pragma unroll
                for (int o = 0; o < 8; ++o) {
                    float ev = ef[o][j];
#pragma unroll
                    for (int h = 0; h < 2; ++h)
#pragma unroll
                        for (int i = 0; i < 4; ++i)
                            acc[h * 4 + i][o] =
                                fmaf(zf[j][h][i], ev, acc[h * 4 + i][o]);
                }
        }
    }

    // ---- d + first-occurrence argmin (u64 keys; d > 0 so bit order = value order)
    float eev[8];
#pragma unroll
    for (int o = 0; o < 8; ++o) eev[o] = ee[cg * 8 + o];

#pragma unroll
    for (int p = 0; p < 8; ++p) {
        float zz = zzs[pg * 8 + p];
        u64 key = ~0ull;
#pragma unroll
        for (int o = 0; o < 8; ++o) {
            float a = acc[p][o];
            float d = __fadd_rn(__fsub_rn(zz, __fadd_rn(a, a)), eev[o]);
            union { float f; unsigned u; } du; du.f = d;
            u64 k2 = ((u64)du.u << 32) | (unsigned)(cg * 8 + o);
            if (k2 < key) key = k2;
        }
        // reduce across the 32 code-group threads (one half-wave)
#pragma unroll
        for (int st = 1; st < 32; st <<= 1) {
            u64 o2 = __shfl_xor(key, st, 32);
            if (o2 < key) key = o2;
        }
        if (cg == 0) iminS[pg * 8 + p] = (int)(key & 0xffffffffu);
    }
    __syncthreads();

    // ---- epilogue: thread -> pixel tx&63, channel-block tx>>6 (32 channels)
    const int cb = tx >> 6;
    const int im = iminS[px];
    const float* __restrict__ eq = emb + (size_t)im * VQ_C + cb * 32;
    const float* __restrict__ zp = zb + px;
    float* __restrict__ op = out + (size_t)b * VQ_CHW + hw0 + px;
    float lsum = 0.0f;
#pragma unroll
    for (int i = 0; i < 8; ++i) {
        f32x4 e4 = *(const f32x4*)(eq + i * 4);        // divergent L2 gather
#pragma unroll
        for (int j = 0; j < 4; ++j) {
            int c = cb * 32 + i * 4 + j;
            float zv   = zp[c * VQ_HW];                // L2-hot, exact bits
            float diff = __fsub_rn(e4[j], zv);
            op[c * VQ_HW] = __fadd_rn(zv, diff);       // coalesced per c
            lsum = fmaf(diff, diff, lsum);
        }
    }
    if (tx < PXB) out[VQ_QELEMS + n0 + tx] = (float)iminS[tx];

    // ---- loss partial
#pragma unroll
    for (int off = 32; off > 0; off >>= 1) lsum += __shfl_down(lsum, off, 64);
    if ((tx & 63) == 0) red[tx >> 6] = lsum;
    __syncthreads();
    if (tx == 0)
        partials[blockIdx.x] = (red[0] + red[1]) + (red[2] + red[3]);
}

__global__ void vq_fin(const float* __restrict__ partials, float* __restrict__ out) {
    double acc = 0.0;
    for (int i = 0; i < NBLK; ++i) acc += (double)partials[i];
    float m = (float)(acc * (1.0 / (double)VQ_QELEMS));
    out[VQ_QELEMS + VQ_NPIX + 0] = 0.25f * m;  // commitment
    out[VQ_QELEMS + VQ_NPIX + 1] = m;          // codebook
}

extern "C" void kernel_launch(void* const* d_in, const int* in_sizes, int n_in,
                              void* d_out, int out_size, void* d_ws, size_t ws_size,
                              hipStream_t stream) {
    const float* z   = (const float*)d_in[0];
    const float* emb = (const float*)d_in[1];
    float* out = (float*)d_out;
    float* ws  = (float*)d_ws;            // [0..255]=ee, [256..)=partials

    vq_prep<<<1, 256, 0, stream>>>(emb, ws);
    vq_main<<<NBLK, 256, 0, stream>>>(z, emb, ws, ws + 256, out);
    vq_fin<<<1, 1, 0, stream>>>(ws + 256, out);
}

// Round 15
// 180.741 us; speedup vs baseline: 5.3689x; 1.0083x over previous
//
#include <hip/hip_runtime.h>

// VectorQuantizer on MI355X (gfx950)
// z:   [B=128, C=128, H=32, W=32] f32 -> pixel n = b*1024 + hw, channel stride 1024
// emb: [K=256, C=128] f32
// out: [quantized_st 16777216][indices 131072][commit 1][codebook 1] (f32)
//
// Exactness contract (verified absmax=0 rounds 2-14 -- DO NOT CHANGE):
//   d_k = fl( fl(zz - 2*s_k) + ee_k )
//   s_k = sequential fmaf over c ascending; zz = sequential fl(z*z) sum
//   first-occurrence argmin == min over u64 keys (d_bits<<32 | k), d > 0
//
// Round-15 = round-14 (164us) with the hot loop's ADDRESSING stripped:
//   - per-thread hoisted byte bases (ebase = es + cg*1152, zbase = zs + pg*32)
//   - per c4-window: ONE v_xor+v_add -> eaddr; 8 ef reads at eaddr offset:o*144
//     (immediate), 8 zf reads at zbase offset:c*256(+16) (immediate, no VALU)
//   r14 spent ~130K cyc/SIMD on address VALU (= the FMA budget itself).

typedef float f32x4 __attribute__((ext_vector_type(4)));
typedef unsigned long long u64;

#define VQ_C      128
#define VQ_K      256
#define VQ_HW     1024
#define VQ_CHW    (VQ_C * VQ_HW)
#define VQ_NPIX   131072
#define VQ_QELEMS 16777216
#define PXB       64
#define NBLK      (VQ_NPIX / PXB)     // 2048
#define CCH       32                  // channels per chunk
#define NCH       4
#define EROW      144                 // es row stride bytes (8x16B + 16B pad)

// ws layout (floats): [0..255] ee[k]; [256..256+NBLK) per-block loss partials
__global__ void vq_prep(const float* __restrict__ emb, float* __restrict__ ws) {
    int k = threadIdx.x;               // 256 threads = 256 codes
    float s = 0.0f;
#pragma unroll
    for (int c = 0; c < VQ_C; ++c) {
        float e = emb[k * VQ_C + c];
        s = __fadd_rn(s, __fmul_rn(e, e));
    }
    ws[k] = s;
}

__global__ __launch_bounds__(256, 3) void vq_main(const float* __restrict__ z,
                                                  const float* __restrict__ emb,
                                                  const float* __restrict__ ee,
                                                  float* __restrict__ partials,
                                                  float* __restrict__ out) {
    __shared__ float zs[CCH * PXB];        // [c][px], 8 KB
    __shared__ char  es[VQ_K * EROW];      // padded swizzled e tile, 36 KB
    __shared__ float zzs[PXB];
    __shared__ int   iminS[PXB];
    __shared__ float red[4];

    const int tx = threadIdx.x;
    const int cg = tx & 31;                // code group: codes cg*8 .. +8
    const int pg = tx >> 5;                // px group:  px  pg*8 .. +8
    const int n0 = blockIdx.x * PXB;
    const int b  = n0 >> 10;
    const int hw0 = n0 & 1023;             // 64 | 1024 -> no b straddle
    const float* __restrict__ zb = z + (size_t)b * VQ_CHW + hw0;

    // ---- phase A: zz per pixel, exact sequential chain (wave 0; ordered
    //      before consumers by the first in-loop barrier)
    if (tx < PXB) {
        float zz = 0.0f;
#pragma unroll
        for (int c = 0; c < VQ_C; ++c) {
            float v = zb[c * VQ_HW + tx];  // 64-lane coalesced per c
            zz = __fadd_rn(zz, __fmul_rn(v, v));
        }
        zzs[tx] = zz;
    }

    float acc[8][8];
#pragma unroll
    for (int p = 0; p < 8; ++p)
#pragma unroll
        for (int o = 0; o < 8; ++o) acc[p][o] = 0.0f;

    const int ci  = tx >> 6;               // z-staging c-lane (wave id)
    const int px  = tx & 63;
    const int swx = (tx >> 3) & 7;         // row's swizzle key (staging)

    // hoisted hot-loop bases (byte pointers, loop-invariant)
    const char* const zbase = (const char*)zs + pg * 32;
    const char* const ebase = es + cg * (8 * EROW);
    const int keysh = (cg & 7) << 4;       // read swizzle key, pre-shifted

#pragma unroll 1
    for (int ch = 0; ch < NCH; ++ch) {
        const int c0 = ch * CCH;
        if (ch) __syncthreads();           // protect tiles from overwrite

        // ---- stage z tile [c][px]: coalesced global reads, free LDS writes
#pragma unroll
        for (int i = 0; i < 8; ++i) {
            int c = i * 4 + ci;
            zs[c * PXB + px] = zb[(c0 + c) * VQ_HW + px];
        }
        // ---- stage e tile: thread tx = code; SEQUENTIAL coalesced loads,
        //      swizzled slot + 144B row stride -> conflict-free writes
        {
            const float* __restrict__ eg = emb + tx * VQ_C + c0;
            char* erow = es + tx * EROW;
#pragma unroll
            for (int c4 = 0; c4 < 8; ++c4) {
                f32x4 v = *(const f32x4*)(eg + c4 * 4);
                *(f32x4*)(erow + ((c4 ^ swx) << 4)) = v;
            }
        }
        __syncthreads();

        // ---- compute: 8 windows of 4 channels; addressing = 1 xor + 1 add
        //      per window, all reads immediate-offset ds_read_b128
#pragma unroll 1
        for (int c4 = 0; c4 < 8; ++c4) {
            const char* eaddr = ebase + ((c4 << 4) ^ keysh);
            f32x4 ef[8];                   // 8 codes x 4 channels
#pragma unroll
            for (int o = 0; o < 8; ++o)
                ef[o] = *(const f32x4*)(eaddr + o * EROW);   // offset:o*144

            f32x4 zf[4][2];                // [j][half]: 8 px of channel c4*4+j
#pragma unroll
            for (int j = 0; j < 4; ++j) {
                zf[j][0] = *(const f32x4*)(zbase + (c4 * 4 + j) * (PXB * 4));
                zf[j][1] = *(const f32x4*)(zbase + (c4 * 4 + j) * (PXB * 4) + 16);
            }
            // c ascending (j outer) => exact per-(px,code) fmaf chain
#pragma unroll
            for (int j = 0; j < 4; ++j)
#pragma unroll
                for (int o = 0; o < 8; ++o) {
                    float ev = ef[o][j];
#pragma unroll
                    for (int h = 0; h < 2; ++h)
#pragma unroll
                        for (int i = 0; i < 4; ++i)
                            acc[h * 4 + i][o] =
                                fmaf(zf[j][h][i], ev, acc[h * 4 + i][o]);
                }
        }
    }

    // ---- d + first-occurrence argmin (u64 keys; d > 0 so bit order = value order)
    float eev[8];
#pragma unroll
    for (int o = 0; o < 8; ++o) eev[o] = ee[cg * 8 + o];

#pragma unroll
    for (int p = 0; p < 8; ++p) {
        float zz = zzs[pg * 8 + p];
        u64 key = ~0ull;
#pragma unroll
        for (int o = 0; o < 8; ++o) {
            float a = acc[p][o];
            float d = __fadd_rn(__fsub_rn(zz, __fadd_rn(a, a)), eev[o]);
            union { float f; unsigned u; } du; du.f = d;
            u64 k2 = ((u64)du.u << 32) | (unsigned)(cg * 8 + o);
            if (k2 < key) key = k2;
        }
        // reduce across the 32 code-group threads (one half-wave)
#pragma unroll
        for (int st = 1; st < 32; st <<= 1) {
            u64 o2 = __shfl_xor(key, st, 32);
            if (o2 < key) key = o2;
        }
        if (cg == 0) iminS[pg * 8 + p] = (int)(key & 0xffffffffu);
    }
    __syncthreads();

    // ---- epilogue: thread -> pixel tx&63, channel-block tx>>6 (32 channels)
    const int cb = tx >> 6;
    const int im = iminS[px];
    const float* __restrict__ eq = emb + (size_t)im * VQ_C + cb * 32;
    const float* __restrict__ zp = zb + px;
    float* __restrict__ op = out + (size_t)b * VQ_CHW + hw0 + px;
    float lsum = 0.0f;
#pragma unroll
    for (int i = 0; i < 8; ++i) {
        f32x4 e4 = *(const f32x4*)(eq + i * 4);        // divergent L2 gather
#pragma unroll
        for (int j = 0; j < 4; ++j) {
            int c = cb * 32 + i * 4 + j;
            float zv   = zp[c * VQ_HW];                // L2-hot, exact bits
            float diff = __fsub_rn(e4[j], zv);
            op[c * VQ_HW] = __fadd_rn(zv, diff);       // coalesced per c
            lsum = fmaf(diff, diff, lsum);
        }
    }
    if (tx < PXB) out[VQ_QELEMS + n0 + tx] = (float)iminS[tx];

    // ---- loss partial
#pragma unroll
    for (int off = 32; off > 0; off >>= 1) lsum += __shfl_down(lsum, off, 64);
    if ((tx & 63) == 0) red[tx >> 6] = lsum;
    __syncthreads();
    if (tx == 0)
        partials[blockIdx.x] = (red[0] + red[1]) + (red[2] + red[3]);
}

__global__ void vq_fin(const float* __restrict__ partials, float* __restrict__ out) {
    double acc = 0.0;
    for (int i = 0; i < NBLK; ++i) acc += (double)partials[i];
    float m = (float)(acc * (1.0 / (double)VQ_QELEMS));
    out[VQ_QELEMS + VQ_NPIX + 0] = 0.25f * m;  // commitment
    out[VQ_QELEMS + VQ_NPIX + 1] = m;          // codebook
}

extern "C" void kernel_launch(void* const* d_in, const int* in_sizes, int n_in,
                              void* d_out, int out_size, void* d_ws, size_t ws_size,
                              hipStream_t stream) {
    const float* z   = (const float*)d_in[0];
    const float* emb = (const float*)d_in[1];
    float* out = (float*)d_out;
    float* ws  = (float*)d_ws;            // [0..255]=ee, [256..)=partials

    vq_prep<<<1, 256, 0, stream>>>(emb, ws);
    vq_main<<<NBLK, 256, 0, stream>>>(z, emb, ws, ws + 256, out);
    vq_fin<<<1, 1, 0, stream>>>(ws + 256, out);
}